// Round 9
// baseline (215.530 us; speedup 1.0000x reference)
//
#include <hip/hip_runtime.h>
#include <hip/hip_bf16.h>

namespace {

constexpr int SEQ = 2048;
constexpr int NB  = 2;
constexpr int DM  = 1024;
constexpr int NHD = 16;
constexpr int DKH = 64;
constexpr int MROWS = SEQ * NB;          // 4096
// 1/sqrt(64) * log2(e): Q is pre-scaled so attn uses raw v_exp_f32 (2^x).
constexpr float SM_SCALE_L2E = 0.125f * 1.44269504088896340736f;
constexpr size_t HT = (size_t)NB * NHD * SEQ * DKH;   // per-tensor head-layout elems

typedef short bf16x8 __attribute__((ext_vector_type(8)));   // 8 bf16 = 4 VGPR
typedef short bf16x4 __attribute__((ext_vector_type(4)));   // 4 bf16 = 2 VGPR
typedef float f32x4  __attribute__((ext_vector_type(4)));

__device__ inline short f2bf(float f) {
    __hip_bfloat16 h = __float2bfloat16(f);
    return *reinterpret_cast<short*>(&h);
}

// Pack two f32 -> two bf16 (RTZ truncation) in ONE v_perm_b32.
__device__ inline unsigned perm_pack_bf16(float hi, float lo) {
    return __builtin_amdgcn_perm(__float_as_uint(hi), __float_as_uint(lo),
                                 0x07060302u);
}

__device__ inline float fexp2(float x) {
#if __has_builtin(__builtin_amdgcn_exp2f)
    return __builtin_amdgcn_exp2f(x);
#else
    return exp2f(x);
#endif
}

// async global->LDS, 16 B per lane. LDS dest = wave-uniform base + lane*16.
__device__ inline void gload_lds16(const short* g, short* l) {
    __builtin_amdgcn_global_load_lds(
        (const __attribute__((address_space(1))) void*)g,
        (__attribute__((address_space(3))) void*)l, 16, 0, 0);
}

// ---------------------------------------------------------------------------
// fp32 -> bf16 cast, activations (y=0..2) + weights (y=3..6) in one launch.
__global__ __launch_bounds__(256)
void cast_all(const float* __restrict__ q, const float* __restrict__ k,
              const float* __restrict__ v, const float* __restrict__ w0,
              const float* __restrict__ w1, const float* __restrict__ w2,
              const float* __restrict__ w3, short* __restrict__ oq,
              short* __restrict__ ok, short* __restrict__ ov,
              short* __restrict__ ow)
{
    const int y = blockIdx.y;
    const float* s;
    short* d;
    if (y < 3) {
        s = y == 0 ? q : y == 1 ? k : v;
        d = y == 0 ? oq : y == 1 ? ok : ov;
    } else {
        if (blockIdx.x >= 512) return;   // weights: DM*DM/8/256 = 512 blocks
        s = y == 3 ? w0 : y == 4 ? w1 : y == 5 ? w2 : w3;
        d = ow + (size_t)(y - 3) * (DM * DM);
    }
    const size_t t = (size_t)blockIdx.x * 256 + threadIdx.x;   // 8 floats/thr
    const float4 a = ((const float4*)s)[2 * t];
    const float4 b = ((const float4*)s)[2 * t + 1];
    short r[8] = {f2bf(a.x), f2bf(a.y), f2bf(a.z), f2bf(a.w),
                  f2bf(b.x), f2bf(b.y), f2bf(b.z), f2bf(b.w)};
    *(bf16x8*)(d + 8 * t) = *(bf16x8*)r;
}

// ---------------------------------------------------------------------------
// Fused QKV MFMA GEMM: tile 128x128, BK=32, 4 waves, XCD-swizzled,
// DOUBLE-BUFFERED at 32 KB LDS (R4/R5 structure — best measured at ~45 us;
// depth-2 vmcnt (R6), full unroll (R7), and 8-wave (R8) all null/regressed,
// so this is the structural floor for the 2-phase schedule at K=1024).
// W rows are [wq;wk;wv] (N=3072); A-operand selected per block by segment.
// seg0 -> Qb (per-head, *SM_SCALE*log2e), seg1 -> Kb (per-head),
// seg2 -> Vt TRANSPOSED [bh][dk][s''] where s'' permutes each 32-block of s
// (s'' = (s&~31)|8*((s>>2)&3)|4*((s>>4)&1)|(s&3)) so attention's PV
// B-fragment (j = 32u+16sig+4q+r) is CONTIGUOUS -> single ds_read_b128.
__global__ __launch_bounds__(256)
void gemm_qkv(const short* __restrict__ X0, const short* __restrict__ X1,
              const short* __restrict__ X2, const short* __restrict__ W,
              const float* __restrict__ b0, const float* __restrict__ b1,
              const float* __restrict__ b2, short* __restrict__ Qb,
              short* __restrict__ Kb, short* __restrict__ Vt)
{
    __shared__ short sAB[2][8192];   // per buf: As[0..4095], Bs[4096..8191]
    const int tid  = threadIdx.x;
    const int lane = tid & 63;
    const int wave = tid >> 6;
    const int i16  = lane & 15;
    const int quad = lane >> 4;

    const int c    = blockIdx.y * gridDim.x + blockIdx.x;  // 0..767
    const int xcd  = c & 7;
    const int idx  = c >> 3;                               // 0..95
    const int m0   = (xcd * 4 + (idx & 3)) * 128;
    const int n0g  = (idx >> 2) * 128;

    const int R0   = (wave & 1) * 64;
    const int C0   = (wave >> 1) * 64;

    const int seg = n0g >> 10;
    const short* X = seg == 0 ? X0 : seg == 1 ? X1 : X2;

    // staging: 4 lanes per 32-col row; 16B slot pre-swizzled by row
    const int rl = lane >> 2;                       // row within wave's 16
    const int sl = (lane & 3) ^ ((rl & 6) >> 1);    // swizzled global 16B slot

    const short* ag[2]; int alo[2];
    const short* bg[2]; int blo[2];
    #pragma unroll
    for (int i = 0; i < 2; ++i) {
        const int row = i * 64 + wave * 16 + rl;
        ag[i] = X + (size_t)(m0 + row) * DM + sl * 8;
        alo[i] = i * 2048 + wave * 512;
        bg[i] = W + (size_t)(n0g + row) * DM + sl * 8;
        blo[i] = 4096 + i * 2048 + wave * 512;
    }

    const int rsw = (quad ^ ((i16 & 6) >> 1)) * 8;  // read-side swizzled slot
    int aoff[4], boff[4];
    #pragma unroll
    for (int rt = 0; rt < 4; ++rt)
        aoff[rt] = (R0 + rt * 16 + i16) * 32 + rsw;
    #pragma unroll
    for (int ct = 0; ct < 4; ++ct)
        boff[ct] = 4096 + (C0 + ct * 16 + i16) * 32 + rsw;

    f32x4 acc[4][4];
    #pragma unroll
    for (int rt = 0; rt < 4; ++rt)
        #pragma unroll
        for (int ct = 0; ct < 4; ++ct) acc[rt][ct] = (f32x4){0.f, 0.f, 0.f, 0.f};

    // prologue: stage ks=0 into buf0
    #pragma unroll
    for (int i = 0; i < 2; ++i) gload_lds16(ag[i], &sAB[0][alo[i]]);
    #pragma unroll
    for (int i = 0; i < 2; ++i) gload_lds16(bg[i], &sAB[0][blo[i]]);
    #pragma unroll
    for (int i = 0; i < 2; ++i) { ag[i] += 32; bg[i] += 32; }
    __syncthreads();

    for (int ks = 0; ks < 32; ++ks) {
        const int p = ks & 1;
        if (ks < 31) {
            #pragma unroll
            for (int i = 0; i < 2; ++i) gload_lds16(ag[i], &sAB[1 - p][alo[i]]);
            #pragma unroll
            for (int i = 0; i < 2; ++i) gload_lds16(bg[i], &sAB[1 - p][blo[i]]);
            #pragma unroll
            for (int i = 0; i < 2; ++i) { ag[i] += 32; bg[i] += 32; }
        }
        const short* buf = sAB[p];
        bf16x8 af[4], bfr[4];
        #pragma unroll
        for (int rt = 0; rt < 4; ++rt) af[rt] = *(const bf16x8*)&buf[aoff[rt]];
        #pragma unroll
        for (int ct = 0; ct < 4; ++ct) bfr[ct] = *(const bf16x8*)&buf[boff[ct]];
        #pragma unroll
        for (int rt = 0; rt < 4; ++rt)
            #pragma unroll
            for (int ct = 0; ct < 4; ++ct)
                acc[rt][ct] = __builtin_amdgcn_mfma_f32_16x16x32_bf16(
                    af[rt], bfr[ct], acc[rt][ct], 0, 0, 0);
        __syncthreads();   // readers done with buf p; prefetch into 1-p drained
    }

    #pragma unroll
    for (int ct = 0; ct < 4; ++ct) {
        const int n = n0g + C0 + ct * 16 + i16;
        const int nn  = n & 1023;
        const int h = nn >> 6, dk = nn & 63;
        const float* bp = seg == 0 ? b0 : seg == 1 ? b1 : b2;
        const float bb = bp[nn];
        const float sc = seg == 0 ? SM_SCALE_L2E : 1.0f;
        #pragma unroll
        for (int rt = 0; rt < 4; ++rt)
            #pragma unroll
            for (int r = 0; r < 4; ++r) {
                const int m = m0 + R0 + rt * 16 + quad * 4 + r;
                const int s = m >> 1, b = m & 1;
                const short val = f2bf((acc[rt][ct][r] + bb) * sc);
                if (seg == 2) {
                    // s-permutation within each 32-block (see kernel comment)
                    const int sp = (s & ~31) | (((s >> 2) & 3) << 3) |
                                   (((s >> 4) & 1) << 2) | (s & 3);
                    Vt[(((size_t)(b * NHD + h) * DKH + dk) << 11) + sp] = val;
                } else {
                    short* dst = seg == 0 ? Qb : Kb;
                    dst[((size_t)(b * NHD + h) * SEQ + s) * DKH + dk] = val;
                }
            }
    }
}

// ---------------------------------------------------------------------------
// Output projection: tile 128(M) x 64(N), XCD-swizzled, DOUBLE-BUFFERED
// staging (prefetch ks+1 before computing ks; one barrier per k-step).
__global__ __launch_bounds__(256)
void gemm_out(const short* __restrict__ X, const short* __restrict__ W,
              const float* __restrict__ bias, float* __restrict__ Y)
{
    __shared__ short sAB[2][12288];   // per buf: As[0..8191], Bs[8192..12287]
    const int tid  = threadIdx.x;
    const int lane = tid & 63;
    const int wave = tid >> 6;
    const int i16  = lane & 15;
    const int quad = lane >> 4;

    const int c   = blockIdx.y * gridDim.x + blockIdx.x;  // 0..511
    const int xcd = c & 7;
    const int idx = c >> 3;
    const int m0  = (xcd * 4 + (idx & 3)) * 128;
    const int n0  = (idx >> 2) * 64;

    const int R0   = wave * 32;

    const int srow = lane >> 3;
    const int ssl  = (lane & 7) ^ srow;

    const short* ag[4]; int alo[4];
    const short* bg[2]; int blo[2];
    #pragma unroll
    for (int i = 0; i < 4; ++i) {
        const int row = i * 32 + wave * 8 + srow;
        ag[i] = X + (size_t)(m0 + row) * DM + ssl * 8;
        alo[i] = i * 2048 + wave * 512;
    }
    #pragma unroll
    for (int i = 0; i < 2; ++i) {
        const int row = i * 32 + wave * 8 + srow;
        bg[i] = W + (size_t)(n0 + row) * DM + ssl * 8;
        blo[i] = 8192 + i * 2048 + wave * 512;
    }

    int aoff[2][2], boff[4][2];
    #pragma unroll
    for (int rt = 0; rt < 2; ++rt)
        #pragma unroll
        for (int kc = 0; kc < 2; ++kc)
            aoff[rt][kc] = (R0 + rt * 16 + i16) * 64 +
                           (((kc * 4 + quad) ^ (i16 & 7)) * 8);
    #pragma unroll
    for (int ct = 0; ct < 4; ++ct)
        #pragma unroll
        for (int kc = 0; kc < 2; ++kc)
            boff[ct][kc] = 8192 + (ct * 16 + i16) * 64 +
                           (((kc * 4 + quad) ^ (i16 & 7)) * 8);

    f32x4 acc[2][4];
    #pragma unroll
    for (int rt = 0; rt < 2; ++rt)
        #pragma unroll
        for (int ct = 0; ct < 4; ++ct) acc[rt][ct] = (f32x4){0.f, 0.f, 0.f, 0.f};

    // prologue: stage ks=0 into buf0
    #pragma unroll
    for (int i = 0; i < 4; ++i) gload_lds16(ag[i], &sAB[0][alo[i]]);
    #pragma unroll
    for (int i = 0; i < 2; ++i) gload_lds16(bg[i], &sAB[0][blo[i]]);
    #pragma unroll
    for (int i = 0; i < 4; ++i) ag[i] += 64;
    #pragma unroll
    for (int i = 0; i < 2; ++i) bg[i] += 64;
    __syncthreads();

    for (int ks = 0; ks < 16; ++ks) {
        const int p = ks & 1;
        if (ks < 15) {
            #pragma unroll
            for (int i = 0; i < 4; ++i) gload_lds16(ag[i], &sAB[1 - p][alo[i]]);
            #pragma unroll
            for (int i = 0; i < 2; ++i) gload_lds16(bg[i], &sAB[1 - p][blo[i]]);
            #pragma unroll
            for (int i = 0; i < 4; ++i) ag[i] += 64;
            #pragma unroll
            for (int i = 0; i < 2; ++i) bg[i] += 64;
        }
        const short* buf = sAB[p];
        #pragma unroll
        for (int kc = 0; kc < 2; ++kc) {
            bf16x8 af[2], bfr[4];
            #pragma unroll
            for (int rt = 0; rt < 2; ++rt) af[rt] = *(const bf16x8*)&buf[aoff[rt][kc]];
            #pragma unroll
            for (int ct = 0; ct < 4; ++ct) bfr[ct] = *(const bf16x8*)&buf[boff[ct][kc]];
            #pragma unroll
            for (int rt = 0; rt < 2; ++rt)
                #pragma unroll
                for (int ct = 0; ct < 4; ++ct)
                    acc[rt][ct] = __builtin_amdgcn_mfma_f32_16x16x32_bf16(
                        af[rt], bfr[ct], acc[rt][ct], 0, 0, 0);
        }
        __syncthreads();
    }

    #pragma unroll
    for (int ct = 0; ct < 4; ++ct) {
        const int n = n0 + ct * 16 + i16;
        const float bb = bias[n];
        #pragma unroll
        for (int rt = 0; rt < 2; ++rt)
            #pragma unroll
            for (int r = 0; r < 4; ++r) {
                const int m = m0 + R0 + rt * 16 + quad * 4 + r;
                Y[(size_t)m * DM + n] = acc[rt][ct][r] + bb;
            }
    }
}

// ---------------------------------------------------------------------------
// MFMA flash attention, full-j, **4-WAVE blocks, 2 blocks/CU** (QBLK=128).
// Same total waves/CU (8) as the R7 1-block version, but TWO independent
// barrier groups: when one block drains at its per-jt barrier, the other
// block's waves keep the MFMA/LDS pipes fed (cross-block overlap, m114).
// Still no combine tail: each wave owns 32 q-rows and walks the full
// j-range; softmax denominator is wave-local.
// PV uses mfma_16x16x32 with j(kappa) = 32u+16*(kappa>>2)+4*quad+(kappa&3):
// A-fragment = concat(pa[2u],pa[2u+1]) (lane-local P), and because Vt's
// s-axis is stored PERMUTED (s'' groups each lane's 8 j's contiguously),
// the B-fragment is ONE ds_read_b128 at chunk (4u+quad)^(i16&7).
// Q is pre-scaled by SM_SCALE*log2e so softmax uses raw v_exp_f32 (2^x).
__global__ __launch_bounds__(256)
void attn_mfma4(const short* __restrict__ Qb, const short* __restrict__ Kb,
                const short* __restrict__ Vtb, short* __restrict__ Xa)
{
    __shared__ short sm[16384];   // 32 KB: buf p at p*8192 shorts

    const int tid  = threadIdx.x;
    const int lane = tid & 63;
    const int wave = tid >> 6;        // 0..3 = q-row group (32 rows each)
    const int i16  = lane & 15;
    const int quad = lane >> 4;

    const int c   = blockIdx.y * gridDim.x + blockIdx.x;   // 0..511
    const int xcd = c & 7;
    const int idx = c >> 3;           // 0..63
    const int bh  = xcd * 4 + (idx & 3);      // same-KV blocks share an XCD
    const int r0  = (idx >> 2) * 128;

    bf16x8 qf[2][2];
    #pragma unroll
    for (int qt = 0; qt < 2; ++qt) {
        const short* qrow =
            Qb + ((size_t)bh * SEQ + r0 + wave * 32 + qt * 16 + i16) * DKH;
        qf[qt][0] = *(const bf16x8*)(qrow + quad * 8);
        qf[qt][1] = *(const bf16x8*)(qrow + 32 + quad * 8);
    }

    f32x4 o[2][4];
    #pragma unroll
    for (int qt = 0; qt < 2; ++qt)
        #pragma unroll
        for (int dkt = 0; dkt < 4; ++dkt) o[qt][dkt] = (f32x4){0.f, 0.f, 0.f, 0.f};
    float lsum[2] = {0.f, 0.f};

    // staging: K chunk (64 rows x 64) at [0..4096), V chunk ([dk=64][j=64])
    // at [4096..8192) within each buffer; each thread stages 2x16B of each.
    const int srow = lane >> 3;              // 0..7
    const int ssl  = (lane & 7) ^ srow;
    const short* kg[2]; const short* vg[2];
    int kls[2], vls[2];
    #pragma unroll
    for (int i = 0; i < 2; ++i) {
        const int row = i * 32 + wave * 8 + srow;
        kg[i] = Kb  + (size_t)bh * SEQ * DKH + (size_t)row * DKH + ssl * 8;
        kls[i] = i * 2048 + wave * 512;
        vg[i] = Vtb + (size_t)bh * DKH * SEQ + (size_t)row * SEQ + ssl * 8;
        vls[i] = 4096 + i * 2048 + wave * 512;
    }

    int koff[4][2];
    #pragma unroll
    for (int t = 0; t < 4; ++t)
        #pragma unroll
        for (int kc = 0; kc < 2; ++kc)
            koff[t][kc] = (t * 16 + i16) * 64 +
                          (((kc * 4 + quad) ^ (i16 & 7)) * 8);
    // V reads: one b128 per (u, dkt); logical 16B chunk = 4u+quad,
    // physical = logical ^ (i16&7) (matches the ssl staging swizzle).
    int voff2[2][4];
    #pragma unroll
    for (int u = 0; u < 2; ++u)
        #pragma unroll
        for (int dkt = 0; dkt < 4; ++dkt)
            voff2[u][dkt] = 4096 + (dkt * 16 + i16) * 64 +
                            (((u * 4 + quad) ^ (i16 & 7)) * 8);

    // prologue: stage jt=0 into buf0
    gload_lds16(kg[0], &sm[kls[0]]);
    gload_lds16(kg[1], &sm[kls[1]]);
    gload_lds16(vg[0], &sm[vls[0]]);
    gload_lds16(vg[1], &sm[vls[1]]);
    __syncthreads();

    for (int jt = 0; jt < 32; ++jt) {
        const int p = jt & 1;
        if (jt < 31) {
            const int bo = (1 - p) * 8192;
            gload_lds16(kg[0] + (size_t)(jt + 1) * 64 * DKH, &sm[bo + kls[0]]);
            gload_lds16(kg[1] + (size_t)(jt + 1) * 64 * DKH, &sm[bo + kls[1]]);
            gload_lds16(vg[0] + (jt + 1) * 64, &sm[bo + vls[0]]);
            gload_lds16(vg[1] + (jt + 1) * 64, &sm[bo + vls[1]]);
        }
        const short* buf = sm + p * 8192;

        bf16x8 kf[4][2];
        #pragma unroll
        for (int t = 0; t < 4; ++t) {
            kf[t][0] = *(const bf16x8*)&buf[koff[t][0]];
            kf[t][1] = *(const bf16x8*)&buf[koff[t][1]];
        }

        bf16x4 pa[2][4];
        #pragma unroll
        for (int qt = 0; qt < 2; ++qt) {
            #pragma unroll
            for (int t = 0; t < 4; ++t) {
                f32x4 st = (f32x4){0.f, 0.f, 0.f, 0.f};
                st = __builtin_amdgcn_mfma_f32_16x16x32_bf16(kf[t][0], qf[qt][0], st, 0, 0, 0);
                st = __builtin_amdgcn_mfma_f32_16x16x32_bf16(kf[t][1], qf[qt][1], st, 0, 0, 0);
                const float e0 = fexp2(st[0]);
                const float e1 = fexp2(st[1]);
                const float e2 = fexp2(st[2]);
                const float e3 = fexp2(st[3]);
                lsum[qt] += (e0 + e1) + (e2 + e3);
                union { unsigned u[2]; bf16x4 v; } pk;
                pk.u[0] = perm_pack_bf16(e1, e0);
                pk.u[1] = perm_pack_bf16(e3, e2);
                pa[qt][t] = pk.v;
            }
        }

        // PV at K=32: A = concat(pa[2u],pa[2u+1]); B = single b128 thanks to
        // the s''-permuted Vt layout.
        #pragma unroll
        for (int u = 0; u < 2; ++u) {
            const bf16x8 a0 = __builtin_shufflevector(
                pa[0][2 * u], pa[0][2 * u + 1], 0, 1, 2, 3, 4, 5, 6, 7);
            const bf16x8 a1 = __builtin_shufflevector(
                pa[1][2 * u], pa[1][2 * u + 1], 0, 1, 2, 3, 4, 5, 6, 7);
            #pragma unroll
            for (int dkt = 0; dkt < 4; ++dkt) {
                const bf16x8 vb = *(const bf16x8*)&buf[voff2[u][dkt]];
                o[0][dkt] = __builtin_amdgcn_mfma_f32_16x16x32_bf16(
                    a0, vb, o[0][dkt], 0, 0, 0);
                o[1][dkt] = __builtin_amdgcn_mfma_f32_16x16x32_bf16(
                    a1, vb, o[1][dkt], 0, 0, 0);
            }
        }
        __syncthreads();   // waves done with buf p; prefetch (jt+1) drained
    }

    // ---- normalize (wave-local denominator) and store ----
    float linv[2];
    #pragma unroll
    for (int qt = 0; qt < 2; ++qt) {
        float v = lsum[qt];
        v += __shfl_xor(v, 16, 64);
        v += __shfl_xor(v, 32, 64);
        linv[qt] = 1.f / v;
    }
    const int b = bh / NHD;
    const int h = bh % NHD;
    #pragma unroll
    for (int qt = 0; qt < 2; ++qt) {
        #pragma unroll
        for (int r = 0; r < 4; ++r) {
            const float iv = __shfl(linv[qt], quad * 4 + r, 64);
            const int row = wave * 32 + qt * 16 + quad * 4 + r;
            const int s = r0 + row;
            const int m = s * NB + b;
            short* op = Xa + (size_t)m * DM + h * DKH;
            #pragma unroll
            for (int dkt = 0; dkt < 4; ++dkt)
                op[dkt * 16 + i16] = f2bf(o[qt][dkt][r] * iv);
        }
    }
}

} // anonymous namespace

extern "C" void kernel_launch(void* const* d_in, const int* in_sizes, int n_in,
                              void* d_out, int out_size, void* d_ws, size_t ws_size,
                              hipStream_t stream)
{
    const float* query = (const float*)d_in[0];
    const float* key_  = (const float*)d_in[1];
    const float* value = (const float*)d_in[2];
    const float* wq    = (const float*)d_in[3];
    const float* bq    = (const float*)d_in[4];
    const float* wk    = (const float*)d_in[5];
    const float* bk    = (const float*)d_in[6];
    const float* wv    = (const float*)d_in[7];
    const float* bv    = (const float*)d_in[8];
    const float* wo    = (const float*)d_in[9];
    const float* bo    = (const float*)d_in[10];
    float* out = (float*)d_out;

    // workspace (56 MB):
    //  0 Qb | 8 Kb | 16 Vt | 24 Xq/Xa | 32 Xk | 40 Xv | 48 Wb[4][DM^2]
    char* ws = (char*)d_ws;
    const size_t HB = HT * sizeof(short);     // 8 MB
    short* Qb = (short*)(ws);
    short* Kb = Qb + HT;
    short* Vt = Qb + 2 * HT;                  // [bh][dk][s''], from gemm_qkv
    short* Xq = (short*)(ws + 3 * HB);
    short* Xa = Xq;                           // alias: Xq dead after QKV gemm
    short* Xk = (short*)(ws + 4 * HB);
    short* Xv = (short*)(ws + 5 * HB);
    short* Wb = (short*)(ws + 6 * HB);        // [wq;wk;wv;wo] bf16

    cast_all<<<dim3(MROWS * DM / (8 * 256), 7), 256, 0, stream>>>(
        query, key_, value, wq, wk, wv, wo, Xq, Xk, Xv, Wb);

    // fused QKV projection (V written pre-transposed + s-permuted), grid 768
    gemm_qkv<<<dim3(MROWS / 128, 3 * DM / 128), 256, 0, stream>>>(
        Xq, Xk, Xv, Wb, bq, bk, bv, Qb, Kb, Vt);

    // full-j attention: 512 blocks x 256 thr (2 independent blocks/CU)
    attn_mfma4<<<dim3(SEQ / 128, NB * NHD), 256, 0, stream>>>(Qb, Kb, Vt, Xa);

    // output projection: double-buffered, grid 512, XCD-swizzled
    gemm_out<<<dim3(MROWS / 128, DM / 64), 256, 0, stream>>>(
        Xa, Wb + 3 * (size_t)DM * DM, bo, out);
}

// Round 10
// 201.366 us; speedup vs baseline: 1.0703x; 1.0703x over previous
//
#include <hip/hip_runtime.h>
#include <hip/hip_bf16.h>

namespace {

constexpr int SEQ = 2048;
constexpr int NB  = 2;
constexpr int DM  = 1024;
constexpr int NHD = 16;
constexpr int DKH = 64;
constexpr int MROWS = SEQ * NB;          // 4096
// 1/sqrt(64) * log2(e): Q is pre-scaled so attn uses raw v_exp_f32 (2^x).
constexpr float SM_SCALE_L2E = 0.125f * 1.44269504088896340736f;
constexpr size_t HT = (size_t)NB * NHD * SEQ * DKH;   // per-tensor head-layout elems

typedef short bf16x8 __attribute__((ext_vector_type(8)));   // 8 bf16 = 4 VGPR
typedef short bf16x4 __attribute__((ext_vector_type(4)));   // 4 bf16 = 2 VGPR
typedef float f32x4  __attribute__((ext_vector_type(4)));

__device__ inline short f2bf(float f) {
    __hip_bfloat16 h = __float2bfloat16(f);
    return *reinterpret_cast<short*>(&h);
}

// Pack two f32 -> two bf16 (RTZ truncation) in ONE v_perm_b32.
__device__ inline unsigned perm_pack_bf16(float hi, float lo) {
    return __builtin_amdgcn_perm(__float_as_uint(hi), __float_as_uint(lo),
                                 0x07060302u);
}

__device__ inline float fexp2(float x) {
#if __has_builtin(__builtin_amdgcn_exp2f)
    return __builtin_amdgcn_exp2f(x);
#else
    return exp2f(x);
#endif
}

// async global->LDS, 16 B per lane. LDS dest = wave-uniform base + lane*16.
__device__ inline void gload_lds16(const short* g, short* l) {
    __builtin_amdgcn_global_load_lds(
        (const __attribute__((address_space(1))) void*)g,
        (__attribute__((address_space(3))) void*)l, 16, 0, 0);
}

// ---------------------------------------------------------------------------
// fp32 -> bf16 cast, activations (y=0..2) + weights (y=3..6) in one launch.
__global__ __launch_bounds__(256)
void cast_all(const float* __restrict__ q, const float* __restrict__ k,
              const float* __restrict__ v, const float* __restrict__ w0,
              const float* __restrict__ w1, const float* __restrict__ w2,
              const float* __restrict__ w3, short* __restrict__ oq,
              short* __restrict__ ok, short* __restrict__ ov,
              short* __restrict__ ow)
{
    const int y = blockIdx.y;
    const float* s;
    short* d;
    if (y < 3) {
        s = y == 0 ? q : y == 1 ? k : v;
        d = y == 0 ? oq : y == 1 ? ok : ov;
    } else {
        if (blockIdx.x >= 512) return;   // weights: DM*DM/8/256 = 512 blocks
        s = y == 3 ? w0 : y == 4 ? w1 : y == 5 ? w2 : w3;
        d = ow + (size_t)(y - 3) * (DM * DM);
    }
    const size_t t = (size_t)blockIdx.x * 256 + threadIdx.x;   // 8 floats/thr
    const float4 a = ((const float4*)s)[2 * t];
    const float4 b = ((const float4*)s)[2 * t + 1];
    short r[8] = {f2bf(a.x), f2bf(a.y), f2bf(a.z), f2bf(a.w),
                  f2bf(b.x), f2bf(b.y), f2bf(b.z), f2bf(b.w)};
    *(bf16x8*)(d + 8 * t) = *(bf16x8*)r;
}

// ---------------------------------------------------------------------------
// Fused QKV MFMA GEMM: tile 128x128, BK=32, 4 waves, XCD-swizzled,
// DOUBLE-BUFFERED at 32 KB LDS (R4/R5 structure — measured best ~45 us;
// depth-2 vmcnt (R6), full unroll (R7), 8-wave (R8) all null/regressed:
// this is the 2-phase schedule's structural floor at K=1024).
// W rows are [wq;wk;wv] (N=3072); A-operand selected per block by segment.
// seg0 -> Qb (per-head, *SM_SCALE*log2e), seg1 -> Kb (per-head),
// seg2 -> Vt TRANSPOSED [bh][dk][s''] where s'' permutes each 32-block of s
// (s'' = (s&~31)|8*((s>>2)&3)|4*((s>>4)&1)|(s&3)) so attention's PV
// B-fragment (j = 32u+16sig+4q+r) is CONTIGUOUS -> single ds_read_b128.
__global__ __launch_bounds__(256)
void gemm_qkv(const short* __restrict__ X0, const short* __restrict__ X1,
              const short* __restrict__ X2, const short* __restrict__ W,
              const float* __restrict__ b0, const float* __restrict__ b1,
              const float* __restrict__ b2, short* __restrict__ Qb,
              short* __restrict__ Kb, short* __restrict__ Vt)
{
    __shared__ short sAB[2][8192];   // per buf: As[0..4095], Bs[4096..8191]
    const int tid  = threadIdx.x;
    const int lane = tid & 63;
    const int wave = tid >> 6;
    const int i16  = lane & 15;
    const int quad = lane >> 4;

    const int c    = blockIdx.y * gridDim.x + blockIdx.x;  // 0..767
    const int xcd  = c & 7;
    const int idx  = c >> 3;                               // 0..95
    const int m0   = (xcd * 4 + (idx & 3)) * 128;
    const int n0g  = (idx >> 2) * 128;

    const int R0   = (wave & 1) * 64;
    const int C0   = (wave >> 1) * 64;

    const int seg = n0g >> 10;
    const short* X = seg == 0 ? X0 : seg == 1 ? X1 : X2;

    // staging: 4 lanes per 32-col row; 16B slot pre-swizzled by row
    const int rl = lane >> 2;                       // row within wave's 16
    const int sl = (lane & 3) ^ ((rl & 6) >> 1);    // swizzled global 16B slot

    const short* ag[2]; int alo[2];
    const short* bg[2]; int blo[2];
    #pragma unroll
    for (int i = 0; i < 2; ++i) {
        const int row = i * 64 + wave * 16 + rl;
        ag[i] = X + (size_t)(m0 + row) * DM + sl * 8;
        alo[i] = i * 2048 + wave * 512;
        bg[i] = W + (size_t)(n0g + row) * DM + sl * 8;
        blo[i] = 4096 + i * 2048 + wave * 512;
    }

    const int rsw = (quad ^ ((i16 & 6) >> 1)) * 8;  // read-side swizzled slot
    int aoff[4], boff[4];
    #pragma unroll
    for (int rt = 0; rt < 4; ++rt)
        aoff[rt] = (R0 + rt * 16 + i16) * 32 + rsw;
    #pragma unroll
    for (int ct = 0; ct < 4; ++ct)
        boff[ct] = 4096 + (C0 + ct * 16 + i16) * 32 + rsw;

    f32x4 acc[4][4];
    #pragma unroll
    for (int rt = 0; rt < 4; ++rt)
        #pragma unroll
        for (int ct = 0; ct < 4; ++ct) acc[rt][ct] = (f32x4){0.f, 0.f, 0.f, 0.f};

    // prologue: stage ks=0 into buf0
    #pragma unroll
    for (int i = 0; i < 2; ++i) gload_lds16(ag[i], &sAB[0][alo[i]]);
    #pragma unroll
    for (int i = 0; i < 2; ++i) gload_lds16(bg[i], &sAB[0][blo[i]]);
    #pragma unroll
    for (int i = 0; i < 2; ++i) { ag[i] += 32; bg[i] += 32; }
    __syncthreads();

    for (int ks = 0; ks < 32; ++ks) {
        const int p = ks & 1;
        if (ks < 31) {
            #pragma unroll
            for (int i = 0; i < 2; ++i) gload_lds16(ag[i], &sAB[1 - p][alo[i]]);
            #pragma unroll
            for (int i = 0; i < 2; ++i) gload_lds16(bg[i], &sAB[1 - p][blo[i]]);
            #pragma unroll
            for (int i = 0; i < 2; ++i) { ag[i] += 32; bg[i] += 32; }
        }
        const short* buf = sAB[p];
        bf16x8 af[4], bfr[4];
        #pragma unroll
        for (int rt = 0; rt < 4; ++rt) af[rt] = *(const bf16x8*)&buf[aoff[rt]];
        #pragma unroll
        for (int ct = 0; ct < 4; ++ct) bfr[ct] = *(const bf16x8*)&buf[boff[ct]];
        #pragma unroll
        for (int rt = 0; rt < 4; ++rt)
            #pragma unroll
            for (int ct = 0; ct < 4; ++ct)
                acc[rt][ct] = __builtin_amdgcn_mfma_f32_16x16x32_bf16(
                    af[rt], bfr[ct], acc[rt][ct], 0, 0, 0);
        __syncthreads();   // readers done with buf p; prefetch into 1-p drained
    }

    #pragma unroll
    for (int ct = 0; ct < 4; ++ct) {
        const int n = n0g + C0 + ct * 16 + i16;
        const int nn  = n & 1023;
        const int h = nn >> 6, dk = nn & 63;
        const float* bp = seg == 0 ? b0 : seg == 1 ? b1 : b2;
        const float bb = bp[nn];
        const float sc = seg == 0 ? SM_SCALE_L2E : 1.0f;
        #pragma unroll
        for (int rt = 0; rt < 4; ++rt)
            #pragma unroll
            for (int r = 0; r < 4; ++r) {
                const int m = m0 + R0 + rt * 16 + quad * 4 + r;
                const int s = m >> 1, b = m & 1;
                const short val = f2bf((acc[rt][ct][r] + bb) * sc);
                if (seg == 2) {
                    // s-permutation within each 32-block (see kernel comment)
                    const int sp = (s & ~31) | (((s >> 2) & 3) << 3) |
                                   (((s >> 4) & 1) << 2) | (s & 3);
                    Vt[(((size_t)(b * NHD + h) * DKH + dk) << 11) + sp] = val;
                } else {
                    short* dst = seg == 0 ? Qb : Kb;
                    dst[((size_t)(b * NHD + h) * SEQ + s) * DKH + dk] = val;
                }
            }
    }
}

// ---------------------------------------------------------------------------
// Output projection: tile 128(M) x 64(N), XCD-swizzled, DOUBLE-BUFFERED
// staging (prefetch ks+1 before computing ks; one barrier per k-step).
__global__ __launch_bounds__(256)
void gemm_out(const short* __restrict__ X, const short* __restrict__ W,
              const float* __restrict__ bias, float* __restrict__ Y)
{
    __shared__ short sAB[2][12288];   // per buf: As[0..8191], Bs[8192..12287]
    const int tid  = threadIdx.x;
    const int lane = tid & 63;
    const int wave = tid >> 6;
    const int i16  = lane & 15;
    const int quad = lane >> 4;

    const int c   = blockIdx.y * gridDim.x + blockIdx.x;  // 0..511
    const int xcd = c & 7;
    const int idx = c >> 3;
    const int m0  = (xcd * 4 + (idx & 3)) * 128;
    const int n0  = (idx >> 2) * 64;

    const int R0   = wave * 32;

    const int srow = lane >> 3;
    const int ssl  = (lane & 7) ^ srow;

    const short* ag[4]; int alo[4];
    const short* bg[2]; int blo[2];
    #pragma unroll
    for (int i = 0; i < 4; ++i) {
        const int row = i * 32 + wave * 8 + srow;
        ag[i] = X + (size_t)(m0 + row) * DM + ssl * 8;
        alo[i] = i * 2048 + wave * 512;
    }
    #pragma unroll
    for (int i = 0; i < 2; ++i) {
        const int row = i * 32 + wave * 8 + srow;
        bg[i] = W + (size_t)(n0 + row) * DM + ssl * 8;
        blo[i] = 8192 + i * 2048 + wave * 512;
    }

    int aoff[2][2], boff[4][2];
    #pragma unroll
    for (int rt = 0; rt < 2; ++rt)
        #pragma unroll
        for (int kc = 0; kc < 2; ++kc)
            aoff[rt][kc] = (R0 + rt * 16 + i16) * 64 +
                           (((kc * 4 + quad) ^ (i16 & 7)) * 8);
    #pragma unroll
    for (int ct = 0; ct < 4; ++ct)
        #pragma unroll
        for (int kc = 0; kc < 2; ++kc)
            boff[ct][kc] = 8192 + (ct * 16 + i16) * 64 +
                           (((kc * 4 + quad) ^ (i16 & 7)) * 8);

    f32x4 acc[2][4];
    #pragma unroll
    for (int rt = 0; rt < 2; ++rt)
        #pragma unroll
        for (int ct = 0; ct < 4; ++ct) acc[rt][ct] = (f32x4){0.f, 0.f, 0.f, 0.f};

    // prologue: stage ks=0 into buf0
    #pragma unroll
    for (int i = 0; i < 4; ++i) gload_lds16(ag[i], &sAB[0][alo[i]]);
    #pragma unroll
    for (int i = 0; i < 2; ++i) gload_lds16(bg[i], &sAB[0][blo[i]]);
    #pragma unroll
    for (int i = 0; i < 4; ++i) ag[i] += 64;
    #pragma unroll
    for (int i = 0; i < 2; ++i) bg[i] += 64;
    __syncthreads();

    for (int ks = 0; ks < 16; ++ks) {
        const int p = ks & 1;
        if (ks < 15) {
            #pragma unroll
            for (int i = 0; i < 4; ++i) gload_lds16(ag[i], &sAB[1 - p][alo[i]]);
            #pragma unroll
            for (int i = 0; i < 2; ++i) gload_lds16(bg[i], &sAB[1 - p][blo[i]]);
            #pragma unroll
            for (int i = 0; i < 4; ++i) ag[i] += 64;
            #pragma unroll
            for (int i = 0; i < 2; ++i) bg[i] += 64;
        }
        const short* buf = sAB[p];
        #pragma unroll
        for (int kc = 0; kc < 2; ++kc) {
            bf16x8 af[2], bfr[4];
            #pragma unroll
            for (int rt = 0; rt < 2; ++rt) af[rt] = *(const bf16x8*)&buf[aoff[rt][kc]];
            #pragma unroll
            for (int ct = 0; ct < 4; ++ct) bfr[ct] = *(const bf16x8*)&buf[boff[ct][kc]];
            #pragma unroll
            for (int rt = 0; rt < 2; ++rt)
                #pragma unroll
                for (int ct = 0; ct < 4; ++ct)
                    acc[rt][ct] = __builtin_amdgcn_mfma_f32_16x16x32_bf16(
                        af[rt], bfr[ct], acc[rt][ct], 0, 0, 0);
        }
        __syncthreads();
    }

    #pragma unroll
    for (int ct = 0; ct < 4; ++ct) {
        const int n = n0 + ct * 16 + i16;
        const float bb = bias[n];
        #pragma unroll
        for (int rt = 0; rt < 2; ++rt)
            #pragma unroll
            for (int r = 0; r < 4; ++r) {
                const int m = m0 + R0 + rt * 16 + quad * 4 + r;
                Y[(size_t)m * DM + n] = acc[rt][ct][r] + bb;
            }
    }
}

// ---------------------------------------------------------------------------
// MFMA flash attention, full-j, QBLK=256, 8 waves (R7 structure — measured
// best; R9's 4-wave/2-block variant regressed).
// NEW: softmax denominator accumulated via MFMA against a ones-vector
// (D = P·1 gives row sums in the SAME C/D layout as O): deletes the 24
// v_add_f32/jt lsum chain from the VALU pipe (which is ~50% busy with exp2,
// the kernel's floor) and removes all epilogue shuffles. The extra 4
// MFMAs/jt ride the ~25%-busy matrix pipe.
// PV uses mfma_16x16x32 with j(kappa) = 32u+16*(kappa>>2)+4*quad+(kappa&3):
// A-fragment = concat(pa[2u],pa[2u+1]) (lane-local P), and because Vt's
// s-axis is stored PERMUTED (s'' groups each lane's 8 j's contiguously),
// the B-fragment is ONE ds_read_b128 at chunk (4u+quad)^(i16&7).
// Q is pre-scaled by SM_SCALE*log2e so softmax uses raw v_exp_f32 (2^x).
__global__ __launch_bounds__(512)
void attn_mfma4(const short* __restrict__ Qb, const short* __restrict__ Kb,
                const short* __restrict__ Vtb, short* __restrict__ Xa)
{
    __shared__ short sm[16384];   // 32 KB: buf p at p*8192 shorts

    const int tid  = threadIdx.x;
    const int lane = tid & 63;
    const int wave = tid >> 6;        // 0..7 = q-row group (32 rows each)
    const int i16  = lane & 15;
    const int quad = lane >> 4;

    const int c   = blockIdx.y * gridDim.x + blockIdx.x;   // 0..255
    const int xcd = c & 7;
    const int idx = c >> 3;           // 0..31
    const int bh  = xcd * 4 + (idx & 3);      // same-KV blocks share an XCD
    const int r0  = (idx >> 2) * 256;

    bf16x8 qf[2][2];
    #pragma unroll
    for (int qt = 0; qt < 2; ++qt) {
        const short* qrow =
            Qb + ((size_t)bh * SEQ + r0 + wave * 32 + qt * 16 + i16) * DKH;
        qf[qt][0] = *(const bf16x8*)(qrow + quad * 8);
        qf[qt][1] = *(const bf16x8*)(qrow + 32 + quad * 8);
    }

    bf16x8 vone;
    #pragma unroll
    for (int i = 0; i < 8; ++i) vone[i] = (short)0x3F80;   // bf16 1.0

    f32x4 o[2][4], ol[2];
    #pragma unroll
    for (int qt = 0; qt < 2; ++qt) {
        #pragma unroll
        for (int dkt = 0; dkt < 4; ++dkt) o[qt][dkt] = (f32x4){0.f, 0.f, 0.f, 0.f};
        ol[qt] = (f32x4){0.f, 0.f, 0.f, 0.f};
    }

    // staging: K chunk (64 rows x 64) at [0..4096), V chunk ([dk=64][j=64])
    // at [4096..8192) within each buffer; 8 waves stage 8 rows each.
    const int srow = lane >> 3;              // 0..7
    const int ssl  = (lane & 7) ^ srow;
    const short* kg = Kb  + (size_t)bh * SEQ * DKH +
                      (size_t)(wave * 8 + srow) * DKH + ssl * 8;
    const short* vg = Vtb + (size_t)bh * DKH * SEQ +
                      (size_t)(wave * 8 + srow) * SEQ + ssl * 8;
    const int kls = wave * 512;
    const int vls = 4096 + wave * 512;

    int koff[4][2];
    #pragma unroll
    for (int t = 0; t < 4; ++t)
        #pragma unroll
        for (int kc = 0; kc < 2; ++kc)
            koff[t][kc] = (t * 16 + i16) * 64 +
                          (((kc * 4 + quad) ^ (i16 & 7)) * 8);
    // V reads: one b128 per (u, dkt); logical 16B chunk = 4u+quad,
    // physical = logical ^ (i16&7) (matches the ssl staging swizzle).
    int voff2[2][4];
    #pragma unroll
    for (int u = 0; u < 2; ++u)
        #pragma unroll
        for (int dkt = 0; dkt < 4; ++dkt)
            voff2[u][dkt] = 4096 + (dkt * 16 + i16) * 64 +
                            (((u * 4 + quad) ^ (i16 & 7)) * 8);

    // prologue: stage jt=0 into buf0
    gload_lds16(kg, &sm[kls]);
    gload_lds16(vg, &sm[vls]);
    __syncthreads();

    for (int jt = 0; jt < 32; ++jt) {
        const int p = jt & 1;
        if (jt < 31) {
            const int bo = (1 - p) * 8192;
            gload_lds16(kg + (size_t)(jt + 1) * 64 * DKH, &sm[bo + kls]);
            gload_lds16(vg + (jt + 1) * 64, &sm[bo + vls]);
        }
        const short* buf = sm + p * 8192;

        bf16x8 kf[4][2];
        #pragma unroll
        for (int t = 0; t < 4; ++t) {
            kf[t][0] = *(const bf16x8*)&buf[koff[t][0]];
            kf[t][1] = *(const bf16x8*)&buf[koff[t][1]];
        }

        bf16x4 pa[2][4];
        #pragma unroll
        for (int qt = 0; qt < 2; ++qt) {
            #pragma unroll
            for (int t = 0; t < 4; ++t) {
                f32x4 st = (f32x4){0.f, 0.f, 0.f, 0.f};
                st = __builtin_amdgcn_mfma_f32_16x16x32_bf16(kf[t][0], qf[qt][0], st, 0, 0, 0);
                st = __builtin_amdgcn_mfma_f32_16x16x32_bf16(kf[t][1], qf[qt][1], st, 0, 0, 0);
                const float e0 = fexp2(st[0]);
                const float e1 = fexp2(st[1]);
                const float e2 = fexp2(st[2]);
                const float e3 = fexp2(st[3]);
                union { unsigned u[2]; bf16x4 v; } pk;
                pk.u[0] = perm_pack_bf16(e1, e0);
                pk.u[1] = perm_pack_bf16(e3, e2);
                pa[qt][t] = pk.v;
            }
        }

        // PV at K=32: A = concat(pa[2u],pa[2u+1]); B = single b128 thanks to
        // the s''-permuted Vt layout. ol += P·1 gives the row sums (l).
        #pragma unroll
        for (int u = 0; u < 2; ++u) {
            const bf16x8 a0 = __builtin_shufflevector(
                pa[0][2 * u], pa[0][2 * u + 1], 0, 1, 2, 3, 4, 5, 6, 7);
            const bf16x8 a1 = __builtin_shufflevector(
                pa[1][2 * u], pa[1][2 * u + 1], 0, 1, 2, 3, 4, 5, 6, 7);
            #pragma unroll
            for (int dkt = 0; dkt < 4; ++dkt) {
                const bf16x8 vb = *(const bf16x8*)&buf[voff2[u][dkt]];
                o[0][dkt] = __builtin_amdgcn_mfma_f32_16x16x32_bf16(
                    a0, vb, o[0][dkt], 0, 0, 0);
                o[1][dkt] = __builtin_amdgcn_mfma_f32_16x16x32_bf16(
                    a1, vb, o[1][dkt], 0, 0, 0);
            }
            ol[0] = __builtin_amdgcn_mfma_f32_16x16x32_bf16(a0, vone, ol[0], 0, 0, 0);
            ol[1] = __builtin_amdgcn_mfma_f32_16x16x32_bf16(a1, vone, ol[1], 0, 0, 0);
        }
        __syncthreads();   // waves done with buf p; prefetch (jt+1) drained
    }

    // ---- normalize (l already per-row in-lane via ol) and store ----
    const int b = bh / NHD;
    const int h = bh % NHD;
    #pragma unroll
    for (int qt = 0; qt < 2; ++qt) {
        #pragma unroll
        for (int r = 0; r < 4; ++r) {
            const float iv = 1.f / ol[qt][r];
            const int row = wave * 32 + qt * 16 + quad * 4 + r;
            const int s = r0 + row;
            const int m = s * NB + b;
            short* op = Xa + (size_t)m * DM + h * DKH;
            #pragma unroll
            for (int dkt = 0; dkt < 4; ++dkt)
                op[dkt * 16 + i16] = f2bf(o[qt][dkt][r] * iv);
        }
    }
}

} // anonymous namespace

extern "C" void kernel_launch(void* const* d_in, const int* in_sizes, int n_in,
                              void* d_out, int out_size, void* d_ws, size_t ws_size,
                              hipStream_t stream)
{
    const float* query = (const float*)d_in[0];
    const float* key_  = (const float*)d_in[1];
    const float* value = (const float*)d_in[2];
    const float* wq    = (const float*)d_in[3];
    const float* bq    = (const float*)d_in[4];
    const float* wk    = (const float*)d_in[5];
    const float* bk    = (const float*)d_in[6];
    const float* wv    = (const float*)d_in[7];
    const float* bv    = (const float*)d_in[8];
    const float* wo    = (const float*)d_in[9];
    const float* bo    = (const float*)d_in[10];
    float* out = (float*)d_out;

    // workspace (56 MB):
    //  0 Qb | 8 Kb | 16 Vt | 24 Xq/Xa | 32 Xk | 40 Xv | 48 Wb[4][DM^2]
    char* ws = (char*)d_ws;
    const size_t HB = HT * sizeof(short);     // 8 MB
    short* Qb = (short*)(ws);
    short* Kb = Qb + HT;
    short* Vt = Qb + 2 * HT;                  // [bh][dk][s''], from gemm_qkv
    short* Xq = (short*)(ws + 3 * HB);
    short* Xa = Xq;                           // alias: Xq dead after QKV gemm
    short* Xk = (short*)(ws + 4 * HB);
    short* Xv = (short*)(ws + 5 * HB);
    short* Wb = (short*)(ws + 6 * HB);        // [wq;wk;wv;wo] bf16

    cast_all<<<dim3(MROWS * DM / (8 * 256), 7), 256, 0, stream>>>(
        query, key_, value, wq, wk, wv, wo, Xq, Xk, Xv, Wb);

    // fused QKV projection (V written pre-transposed + s-permuted), grid 768
    gemm_qkv<<<dim3(MROWS / 128, 3 * DM / 128), 256, 0, stream>>>(
        Xq, Xk, Xv, Wb, bq, bk, bv, Qb, Kb, Vt);

    // full-j attention: 256 blocks x 512 thr (1 block/CU)
    attn_mfma4<<<dim3(SEQ / 256, NB * NHD), 512, 0, stream>>>(Qb, Kb, Vt, Xa);

    // output projection: double-buffered, grid 512, XCD-swizzled
    gemm_out<<<dim3(MROWS / 128, DM / 64), 256, 0, stream>>>(
        Xa, Wb + 3 * (size_t)DM * DM, bo, out);
}